// Round 4
// baseline (524.632 us; speedup 1.0000x reference)
//
#include <hip/hip_runtime.h>
#include <cmath>

typedef __bf16  v8bf  __attribute__((ext_vector_type(8)));
typedef float   v4f   __attribute__((ext_vector_type(4)));

#define HH 56
#define WW2 56
#define SS 3
#define HEADS 6
#define DIM 192
#define HID 768
#define NTOK 49
#define NWIN 2048            // BATCH * 64
#define MTOT (NWIN * NTOK)   // 100352
#define SCALE 0.17677669529663687f

// async global->LDS, 16B per lane. LDS dest must be wave-uniform base + lane*16.
__device__ __forceinline__ void async_cp16(const __bf16* g, __bf16* l) {
    __builtin_amdgcn_global_load_lds(
        (const __attribute__((address_space(1))) void*)g,
        (__attribute__((address_space(3))) void*)l,
        16, 0, 0);
}

// raw workgroup barrier (no implicit vmcnt(0) drain, unlike __syncthreads)
__device__ __forceinline__ void wg_barrier() {
    __builtin_amdgcn_sched_barrier(0);
    __builtin_amdgcn_s_barrier();
    __builtin_amdgcn_sched_barrier(0);
}
#define WAIT_LGKM0() asm volatile("s_waitcnt lgkmcnt(0)" ::: "memory")
#define WAIT_VM(n)   asm volatile("s_waitcnt vmcnt(" #n ")" ::: "memory")

// fast exact-accuracy GELU: erf via Abramowitz-Stegun 7.1.26 (|err|<1.5e-7,
// far below bf16 rounding).
__device__ __forceinline__ float fast_gelu(float x) {
    float z = fabsf(x) * 0.70710678118654752f;
    float t = __builtin_amdgcn_rcpf(1.f + 0.3275911f * z);
    float poly = t * (0.254829592f + t * (-0.284496736f +
                 t * (1.421413741f + t * (-1.453152027f + t * 1.061405429f))));
    float er = 1.f - poly * __expf(-z * z);
    er = (x < 0.f) ? -er : er;
    return 0.5f * x * (1.f + er);
}

// ---------------------------------------------------------------------------
// Weight transpose + f32->bf16 cast: out[n*K + k] = (bf16)in[k*N + n]
// ---------------------------------------------------------------------------
__global__ void k_transpose(const float* __restrict__ in, __bf16* __restrict__ out,
                            int K, int N) {
    int idx = blockIdx.x * 256 + threadIdx.x;
    if (idx >= K * N) return;
    int n = idx / K, k = idx - n * K;
    out[idx] = (__bf16)in[k * N + n];
}

// ---------------------------------------------------------------------------
// Pre-swizzled fc1 weights (staged via global_load_lds, linear LDS dest,
// XOR-swizzled image; guideline 21).
// fc1S: bf16 idx = n*192 + b16*8 + j  holds fc1_w[(8*(b16^(n&7))+j)*768 + n]
//   -> LDS image: row n_local (stride 384B), byte = (k*2) ^ ((n&7)<<4)
// ---------------------------------------------------------------------------
__global__ void k_prep_fc1(const float* __restrict__ w, __bf16* __restrict__ o) {
    int idx = blockIdx.x * 256 + threadIdx.x;
    if (idx >= HID * DIM) return;
    int n = idx / DIM, rem = idx - n * DIM;
    int b16 = rem >> 3, j = rem & 7;
    int k = 8 * (b16 ^ (n & 7)) + j;
    o[idx] = (__bf16)w[k * HID + n];
}

// ---------------------------------------------------------------------------
// fc2 weights, 32-k chunks, LINEAR image [192 n][32 k] (stride-64B rows are
// bank-balanced for the b128 fragment reads -- no swizzle needed).
// idx = hc*(192*32) + n*32 + k  holds fc2_w[(hc*32 + k)*192 + n]
// ---------------------------------------------------------------------------
__global__ void k_prep_fc2(const float* __restrict__ w, __bf16* __restrict__ o) {
    int idx = blockIdx.x * 256 + threadIdx.x;
    if (idx >= HID * DIM) return;
    int hc = idx / (192 * 32);
    int rem = idx - hc * 192 * 32;
    int n = rem >> 5, k = rem & 31;
    o[idx] = (__bf16)w[(hc * 32 + k) * DIM + n];
}

// ---------------------------------------------------------------------------
// Precompute bias tables: bias_tab[type][h][m][n], type in {0=interior,
// 1=right-edge, 2=bottom-edge, 3=corner}.
// ---------------------------------------------------------------------------
__global__ void k_bias(const float* __restrict__ rpb, float* __restrict__ bt) {
    int type = blockIdx.x, h = blockIdx.y;
    for (int idx = threadIdx.x; idx < 4096; idx += 256) {
        int m = idx >> 6, n = idx & 63;
        float v;
        if (m >= 49) v = -1e9f;
        else if (n >= 49) v = 0.f;
        else {
            int ni = n / 7, nj = n % 7, mi = m / 7, mj = m % 7;
            v = rpb[((ni - mi + 6) * 13 + (nj - mj + 6)) * 6 + h];
            int rin = (type & 2) ? ((ni < 4) ? 1 : 2) : 0;
            int rjn = (type & 1) ? ((nj < 4) ? 1 : 2) : 0;
            int rim = (type & 2) ? ((mi < 4) ? 1 : 2) : 0;
            int rjm = (type & 1) ? ((mj < 4) ? 1 : 2) : 0;
            if (rin * 3 + rjn != rim * 3 + rjm) v -= 100.f;
        }
        bt[((size_t)(type * HEADS + h) * 64 + m) * 64 + n] = v;
    }
}

// ---------------------------------------------------------------------------
// LN1 + cyclic shift(-3,-3) + window partition. x f32 -> xw bf16 [w*49+p][c].
// ---------------------------------------------------------------------------
__global__ __launch_bounds__(256) void k_ln1win(const float* __restrict__ x,
                                                const float* __restrict__ g,
                                                const float* __restrict__ bt,
                                                __bf16* __restrict__ xw) {
    int wv = threadIdx.x >> 6, lane = threadIdx.x & 63;
    int t = blockIdx.x * 4 + wv;
    int w = t / NTOK, p = t - w * NTOK;
    int b = w >> 6, wi = w & 63;
    int i = (wi >> 3) * 7 + p / 7;
    int j = (wi & 7) * 7 + p % 7;
    int io = i + SS; if (io >= HH) io -= HH;
    int jo = j + SS; if (jo >= WW2) jo -= WW2;
    const float* src = x + ((size_t)(b * 3136 + io * 56 + jo)) * DIM;
    float v0 = src[lane], v1 = src[lane + 64], v2 = src[lane + 128];
    float s = v0 + v1 + v2, s2 = v0 * v0 + v1 * v1 + v2 * v2;
    #pragma unroll
    for (int off = 1; off < 64; off <<= 1) {
        s  += __shfl_xor(s, off);
        s2 += __shfl_xor(s2, off);
    }
    float mu = s * (1.f / 192.f);
    float rstd = rsqrtf(s2 * (1.f / 192.f) - mu * mu + 1e-5f);
    __bf16* dst = xw + (size_t)t * DIM;
    dst[lane]       = (__bf16)((v0 - mu) * rstd * g[lane]       + bt[lane]);
    dst[lane + 64]  = (__bf16)((v1 - mu) * rstd * g[lane + 64]  + bt[lane + 64]);
    dst[lane + 128] = (__bf16)((v2 - mu) * rstd * g[lane + 128] + bt[lane + 128]);
}

// ---------------------------------------------------------------------------
// 128x128-tile MFMA GEMM, double-buffered LDS + counted vmcnt (T3/T4):
// stage k+2 is issued right after the compute barrier; waits are vmcnt(4)
// (my wave's 4 in-flight loads of the NEXT stage remain), never 0 mid-loop.
// MODE 0: qkv scatter -> qb/kb/vb [w,h,t,32] bf16 (q scaled).
// MODE 1: proj -> outf = x1 (window-reverse scatter) + xres, f32
// ---------------------------------------------------------------------------
template<int KDIM, int NDIM, int MODE>
__global__ __launch_bounds__(256) void k_gemm128(const __bf16* __restrict__ A,
                                                 const __bf16* __restrict__ Wt,
                                                 const float* __restrict__ bias,
                                                 __bf16* __restrict__ outb,
                                                 const float* __restrict__ x1in,
                                                 float* __restrict__ outf,
                                                 const float* __restrict__ xres) {
    __shared__ __bf16 lA[2][128 * 32];
    __shared__ __bf16 lB[2][128 * 32];
    const int tid = threadIdx.x;
    const int m0 = blockIdx.x * 128, n0 = blockIdx.y * 128;
    const int wv = tid >> 6, lane = tid & 63;
    const int wm = (wv >> 1) * 64, wn = (wv & 1) * 64;
    const int lrow = lane & 15, lq = lane >> 4;
    const int grow = tid >> 2, gkc = (tid & 3) * 8;

    auto stage = [&](int kk, int b) {
        #pragma unroll
        for (int c = 0; c < 2; c++) {
            int r = grow + c * 64;
            async_cp16(A + (size_t)(m0 + r) * KDIM + kk + gkc, lA[b] + tid * 8 + c * 2048);
            int rb = n0 + r;
            if (NDIM % 128) rb = (rb < NDIM) ? rb : (NDIM - 1);
            async_cp16(Wt + (size_t)rb * KDIM + kk + gkc, lB[b] + tid * 8 + c * 2048);
        }
    };
    stage(0, 0);
    stage(32, 1);

    v4f acc[4][4] = {};
    #pragma unroll
    for (int kk = 0; kk < KDIM; kk += 32) {
        const int b = (kk >> 5) & 1;
        if (kk + 32 < KDIM) { WAIT_VM(4); } else { WAIT_VM(0); }
        wg_barrier();
        v8bf af[4], bf[4];
        #pragma unroll
        for (int i = 0; i < 4; i++) {
            af[i] = *(const v8bf*)(lA[b] + (wm + i * 16 + lrow) * 32 + lq * 8);
            bf[i] = *(const v8bf*)(lB[b] + (wn + i * 16 + lrow) * 32 + lq * 8);
        }
        #pragma unroll
        for (int i = 0; i < 4; i++)
        #pragma unroll
        for (int j = 0; j < 4; j++)
            acc[i][j] = __builtin_amdgcn_mfma_f32_16x16x32_bf16(af[i], bf[j], acc[i][j], 0, 0, 0);
        wg_barrier();
        if (kk + 64 < KDIM) stage(kk + 64, b);
    }
    #pragma unroll
    for (int i = 0; i < 4; i++)
    #pragma unroll
    for (int j = 0; j < 4; j++) {
        int col = n0 + wn + j * 16 + lrow;
        if (NDIM % 128 && col >= NDIM) continue;
        float bv = bias[col];
        #pragma unroll
        for (int r = 0; r < 4; r++) {
            int row = m0 + wm + i * 16 + lq * 4 + r;
            float v = acc[i][j][r] + bv;
            if (MODE == 0) {
                __bf16* kbp = outb + (size_t)MTOT * DIM;
                __bf16* vbp = kbp + (size_t)MTOT * DIM;
                int which = col / DIM, rem = col - which * DIM;
                int hh = rem >> 5, d = rem & 31;
                int w = row / NTOK, p = row - w * NTOK;
                size_t off = ((size_t)(w * HEADS + hh) * NTOK + p) * 32 + d;
                if (which == 0)      outb[off] = (__bf16)(v * SCALE);
                else if (which == 1) kbp[off] = (__bf16)v;
                else                 vbp[off] = (__bf16)v;
            } else {  // proj: window-reverse + unshift + residual
                int w = row / NTOK, p = row - w * NTOK;
                int bimg = w >> 6, wi = w & 63;
                int ii = (wi >> 3) * 7 + p / 7;
                int jj = (wi & 7) * 7 + p % 7;
                int io = ii + SS; if (io >= HH) io -= HH;
                int jo = jj + SS; if (jo >= WW2) jo -= WW2;
                size_t o = ((size_t)(bimg * 3136 + io * 56 + jo)) * DIM + col;
                outf[o] = v + xres[o];
            }
        }
    }
}

// ---------------------------------------------------------------------------
// MFMA windowed attention: one wave per (window, head), 64-thread blocks.
// ---------------------------------------------------------------------------
__global__ __launch_bounds__(64) void k_attn_mfma(const __bf16* __restrict__ qb,
                                                  const float* __restrict__ bias_tab,
                                                  __bf16* __restrict__ ao) {
    __shared__ __bf16 Pl[64 * 72];
    __shared__ __bf16 VTl[32 * 72];
    const __bf16* kb = qb + (size_t)MTOT * DIM;
    const __bf16* vb = kb + (size_t)MTOT * DIM;
    int wh = blockIdx.x;
    int w = wh / HEADS, h = wh - w * HEADS;
    int lane = threadIdx.x & 63;
    int c = lane & 15, q = lane >> 4;
    const size_t base = (size_t)wh * (NTOK * 32);

    for (int idx = lane; idx < 32 * 16; idx += 64)
        VTl[(idx >> 4) * 72 + 48 + (idx & 15)] = (__bf16)0.f;
    #pragma unroll
    for (int it = 0; it < 4; it++) {
        int idx = it * 64 + lane;
        if (idx < NTOK * 4) {
            int t = idx >> 2, d0 = (idx & 3) * 8;
            v8bf vv = *(const v8bf*)(vb + base + t * 32 + d0);
            #pragma unroll
            for (int ii = 0; ii < 8; ii++) VTl[(d0 + ii) * 72 + t] = vv[ii];
        }
    }
    v8bf af[4], bf[4];
    #pragma unroll
    for (int rt = 0; rt < 4; rt++) {
        int t = rt * 16 + c; t = (t > 48) ? 48 : t;
        af[rt] = *(const v8bf*)(qb + base + t * 32 + q * 8);
        bf[rt] = *(const v8bf*)(kb + base + t * 32 + q * 8);
    }
    v4f S[4][4] = {};
    #pragma unroll
    for (int rt = 0; rt < 4; rt++)
    #pragma unroll
    for (int ct = 0; ct < 4; ct++)
        S[rt][ct] = __builtin_amdgcn_mfma_f32_16x16x32_bf16(af[rt], bf[ct], S[rt][ct], 0, 0, 0);
    int wi = w & 63;
    int type = (((wi >> 3) == 7) ? 2 : 0) + (((wi & 7) == 7) ? 1 : 0);
    const float* bt = bias_tab + (size_t)(type * HEADS + h) * 4096;
    #pragma unroll
    for (int rt = 0; rt < 4; rt++)
    #pragma unroll
    for (int ct = 0; ct < 4; ct++) {
        v4f bv = *(const v4f*)(bt + (ct * 16 + c) * 64 + rt * 16 + q * 4);
        S[rt][ct] += bv;
    }
    v4f mx4[4], inv4[4];
    #pragma unroll
    for (int rt = 0; rt < 4; rt++) {
        v4f m;
        #pragma unroll
        for (int r = 0; r < 4; r++)
            m[r] = fmaxf(fmaxf(S[rt][0][r], S[rt][1][r]), fmaxf(S[rt][2][r], S[rt][3][r]));
        #pragma unroll
        for (int off = 1; off < 16; off <<= 1) {
            #pragma unroll
            for (int r = 0; r < 4; r++) m[r] = fmaxf(m[r], __shfl_xor(m[r], off));
        }
        mx4[rt] = m;
    }
    #pragma unroll
    for (int rt = 0; rt < 4; rt++) {
        v4f dsum = {};
        #pragma unroll
        for (int ct = 0; ct < 4; ct++) {
            #pragma unroll
            for (int r = 0; r < 4; r++) {
                float e = __expf(S[rt][ct][r] - mx4[rt][r]);
                dsum[r] += e;
                Pl[(rt * 16 + q * 4 + r) * 72 + ct * 16 + c] = (__bf16)e;
            }
        }
        #pragma unroll
        for (int off = 1; off < 16; off <<= 1) {
            #pragma unroll
            for (int r = 0; r < 4; r++) dsum[r] += __shfl_xor(dsum[r], off);
        }
        #pragma unroll
        for (int r = 0; r < 4; r++) inv4[rt][r] = 1.f / dsum[r];
    }
    __syncthreads();
    v4f O[4][2] = {};
    #pragma unroll
    for (int k2 = 0; k2 < 2; k2++) {
        v8bf pa[4], pb[2];
        #pragma unroll
        for (int rt = 0; rt < 4; rt++)
            pa[rt] = *(const v8bf*)(Pl + (rt * 16 + c) * 72 + k2 * 32 + q * 8);
        #pragma unroll
        for (int ct = 0; ct < 2; ct++)
            pb[ct] = *(const v8bf*)(VTl + (ct * 16 + c) * 72 + k2 * 32 + q * 8);
        #pragma unroll
        for (int rt = 0; rt < 4; rt++)
        #pragma unroll
        for (int ct = 0; ct < 2; ct++)
            O[rt][ct] = __builtin_amdgcn_mfma_f32_16x16x32_bf16(pa[rt], pb[ct], O[rt][ct], 0, 0, 0);
    }
    __bf16* aop = ao + (size_t)(w * NTOK) * DIM + h * 32;
    #pragma unroll
    for (int rt = 0; rt < 4; rt++)
    #pragma unroll
    for (int r = 0; r < 4; r++) {
        int row = rt * 16 + q * 4 + r;
        if (row < NTOK) {
            #pragma unroll
            for (int ct = 0; ct < 2; ct++)
                aop[(size_t)row * DIM + ct * 16 + c] = (__bf16)(O[rt][ct][r] * inv4[rt][r]);
        }
    }
}

// ---------------------------------------------------------------------------
// Fused MLP v4: LN2 + fc1 + GELU + fc2 + residual. BM=64, HC=32 (24 chunks).
// Same counted-vmcnt ping-pong as v3 but LDS shrunk to 40,704 B ->
// 4 blocks/CU (4 waves/SIMD) for real TLP.  Numerically identical to v3
// (same K=32 MFMA accumulation sequence).
//
// LDS map (40,704 B):
//   [0,24576)      aT (LN2 image, 64 x 384B swz)  -> recycled after afr read:
//     [0,12288)      bufX: fc2 chunk [192 n][32 k] linear (stride-64B rows)
//     [12288,16384)  lH:   GELU chunk [64 rows][32 cols] linear (stride 64B)
//   [24576,36864)  bufY: fc1 chunk [32 n][192 k] swz (stride-384B rows)
//   [36864,39936)  lB1 (768 f32);  [39936,40704) lB2 (192 f32)
// Stage = 3 async_cp16/thread -> waits are vmcnt(3).
// ---------------------------------------------------------------------------
__global__ __launch_bounds__(256, 4) void k_mlp_fused(
        const float* __restrict__ x1,
        const float* __restrict__ n2g, const float* __restrict__ n2b,
        const __bf16* __restrict__ fc1S, const float* __restrict__ fc1b,
        const __bf16* __restrict__ fc2S, const float* __restrict__ fc2b,
        float* __restrict__ out) {
    __shared__ __align__(16) char sm[40704];
    char* bufX = sm;                     // 12288 (after LN)
    char* lH   = sm + 12288;             //  4096 (after LN)
    char* bufY = sm + 24576;             // 12288
    float* lB1 = (float*)(sm + 36864);   //  3072
    float* lB2 = (float*)(sm + 39936);   //   768
    const int tid = threadIdx.x;
    const int wv = tid >> 6, lane = tid & 63;
    const int lrow = lane & 15, lq = lane >> 4;
    const int m0 = blockIdx.x * 64;

    // prefetch W1 chunk 0 into bufY (drained by LN's value-consumption waits)
    #pragma unroll
    for (int p = 0; p < 3; ++p)
        async_cp16(fc1S + p * 2048 + tid * 8, (__bf16*)bufY + p * 2048 + tid * 8);

    // stage biases to LDS (loop body must stay free of extra vmem ops)
    #pragma unroll
    for (int p = 0; p < 3; ++p) lB1[p * 256 + tid] = fc1b[p * 256 + tid];
    if (tid < 192) lB2[tid] = fc2b[tid];

    // ---- Phase 0: LN2 of 64 rows into aT=sm[0..24576) (swz); 16 rows/wave
    {
        float g0 = n2g[lane], g1 = n2g[lane + 64], g2 = n2g[lane + 128];
        float b0 = n2b[lane], b1 = n2b[lane + 64], b2 = n2b[lane + 128];
        #pragma unroll 4
        for (int it = 0; it < 16; ++it) {
            int row = wv * 16 + it;
            const float* src = x1 + (size_t)(m0 + row) * DIM;
            float v0 = src[lane], v1 = src[lane + 64], v2 = src[lane + 128];
            float s = v0 + v1 + v2, s2 = v0 * v0 + v1 * v1 + v2 * v2;
            #pragma unroll
            for (int off = 1; off < 64; off <<= 1) {
                s  += __shfl_xor(s, off);
                s2 += __shfl_xor(s2, off);
            }
            float mu = s * (1.f / 192.f);
            float rstd = rsqrtf(s2 * (1.f / 192.f) - mu * mu + 1e-5f);
            char* rb = sm + row * 384;
            int xo = (row & 7) << 4;
            *(__bf16*)(rb + ((lane * 2)       ^ xo)) = (__bf16)((v0 - mu) * rstd * g0 + b0);
            *(__bf16*)(rb + ((lane * 2 + 128) ^ xo)) = (__bf16)((v1 - mu) * rstd * g1 + b1);
            *(__bf16*)(rb + ((lane * 2 + 256) ^ xo)) = (__bf16)((v2 - mu) * rstd * g2 + b2);
        }
    }
    WAIT_LGKM0();
    wg_barrier();        // aT + biases visible; W1[0] landed

    // ---- A fragments -> registers; aT space then recycled (bufX/lH) ----
    const int wm  = (wv >> 1) * 32;   // row-tile base
    const int wc1 = (wv & 1) * 16;    // fc1 col base within 32-chunk
    const int wn  = (wv & 1) * 96;    // fc2 col base (192 total)
    v8bf afr[2][6];
    #pragma unroll
    for (int i = 0; i < 2; ++i) {
        int ra = wm + i * 16 + lrow;
        #pragma unroll
        for (int ks = 0; ks < 6; ++ks)
            afr[i][ks] = *(const v8bf*)(sm + ra * 384 + ((ks * 64 + lq * 16) ^ ((ra & 7) << 4)));
    }
    WAIT_LGKM0();        // frags in VGPRs before DMA overwrites the region
    wg_barrier();

    // issue W2 chunk 0 into bufX (lands under fc1[0] compute)
    #pragma unroll
    for (int p = 0; p < 3; ++p)
        async_cp16(fc2S + p * 2048 + tid * 8, (__bf16*)bufX + p * 2048 + tid * 8);

    v4f oacc[2][6] = {};
    for (int hc = 0; hc < 24; ++hc) {
        int hn = hc + 1; if (hn == 24) hn = 0;   // wrapped: keeps waits uniform
        // ---- fc1: hid_chunk[64][32] = afr * W1[hc](bufY)^T ----
        v4f hacc[2] = {};
        __builtin_amdgcn_s_setprio(1);
        #pragma unroll
        for (int ks = 0; ks < 6; ++ks) {
            int rw = wc1 + lrow;
            v8bf bw = *(const v8bf*)(bufY + rw * 384 + ((ks * 64 + lq * 16) ^ ((rw & 7) << 4)));
            #pragma unroll
            for (int i = 0; i < 2; ++i)
                hacc[i] = __builtin_amdgcn_mfma_f32_16x16x32_bf16(afr[i][ks], bw, hacc[i], 0, 0, 0);
        }
        __builtin_amdgcn_s_setprio(0);
        // ---- bias + fast GELU -> lH (linear, stride-64B rows) ----
        {
            float bv = lB1[hc * 32 + wc1 + lrow];
            #pragma unroll
            for (int i = 0; i < 2; ++i)
            #pragma unroll
            for (int r = 0; r < 4; ++r) {
                int row = wm + i * 16 + lq * 4 + r;
                int col = wc1 + lrow;
                float hv = hacc[i][r] + bv;
                *(__bf16*)(lH + row * 64 + col * 2) = (__bf16)fast_gelu(hv);
            }
        }
        WAIT_LGKM0();
        wg_barrier();                      // lH visible; bufY reads done everywhere
        {   // issue W1[hn] -> bufY (lands under fc2 compute)
            const __bf16* s1 = fc1S + (size_t)hn * (32 * 192);
            #pragma unroll
            for (int p = 0; p < 3; ++p)
                async_cp16(s1 + p * 2048 + tid * 8, (__bf16*)bufY + p * 2048 + tid * 8);
        }
        WAIT_VM(3);                        // W2[hc] (older 3) landed; W1[hn] in flight
        wg_barrier();                      // -> all waves' W2[hc] landed
        // ---- fc2: oacc += lH[64x32] * W2[hc](bufX)^T (192 cols, K=32) ----
        __builtin_amdgcn_s_setprio(1);
        {
            v8bf pa[2], pb[6];
            #pragma unroll
            for (int i = 0; i < 2; ++i) {
                int ra = wm + i * 16 + lrow;
                pa[i] = *(const v8bf*)(lH + ra * 64 + lq * 16);
            }
            #pragma unroll
            for (int j = 0; j < 6; ++j) {
                int rw = wn + j * 16 + lrow;
                pb[j] = *(const v8bf*)(bufX + rw * 64 + lq * 16);
            }
            #pragma unroll
            for (int i = 0; i < 2; ++i)
            #pragma unroll
            for (int j = 0; j < 6; ++j)
                oacc[i][j] = __builtin_amdgcn_mfma_f32_16x16x32_bf16(pa[i], pb[j], oacc[i][j], 0, 0, 0);
        }
        __builtin_amdgcn_s_setprio(0);
        WAIT_LGKM0();
        wg_barrier();                      // bufX/lH reads done everywhere
        {   // issue W2[hn] -> bufX (lands under next fc1 compute)
            const __bf16* s2 = fc2S + (size_t)hn * (192 * 32);
            #pragma unroll
            for (int p = 0; p < 3; ++p)
                async_cp16(s2 + p * 2048 + tid * 8, (__bf16*)bufX + p * 2048 + tid * 8);
        }
        WAIT_VM(3);                        // W1[hn] (older 3) landed; W2[hn] in flight
        wg_barrier();
    }
    WAIT_VM(0);   // drain wrapped redundant loads
    // ---- epilogue: out = oacc + fc2b + x1 (residual) ----
    #pragma unroll
    for (int i = 0; i < 2; ++i)
    #pragma unroll
    for (int j = 0; j < 6; ++j) {
        int col = wn + j * 16 + lrow;
        float bv = lB2[col];
        #pragma unroll
        for (int r = 0; r < 4; ++r) {
            int row = m0 + wm + i * 16 + lq * 4 + r;
            size_t o = (size_t)row * DIM + col;
            out[o] = oacc[i][j][r] + bv + x1[o];
        }
    }
}

// ---------------------------------------------------------------------------
extern "C" void kernel_launch(void* const* d_in, const int* in_sizes, int n_in,
                              void* d_out, int out_size, void* d_ws, size_t ws_size,
                              hipStream_t stream) {
    const float* x      = (const float*)d_in[0];
    const float* n1g    = (const float*)d_in[1];
    const float* n1b    = (const float*)d_in[2];
    const float* qkv_w  = (const float*)d_in[3];
    const float* qkv_b  = (const float*)d_in[4];
    const float* rpb    = (const float*)d_in[5];
    const float* proj_w = (const float*)d_in[6];
    const float* proj_b = (const float*)d_in[7];
    const float* n2g    = (const float*)d_in[8];
    const float* n2b    = (const float*)d_in[9];
    const float* fc1_w  = (const float*)d_in[10];
    const float* fc1_b  = (const float*)d_in[11];
    const float* fc2_w  = (const float*)d_in[12];
    const float* fc2_b  = (const float*)d_in[13];
    float* outp = (float*)d_out;

    char* ws = (char*)d_ws;
    const size_t SZA = (size_t)MTOT * DIM * 2;      // 38,535,168
    __bf16* xw = (__bf16*)ws;
    __bf16* qb = (__bf16*)(ws + SZA);
    float*  x1 = (float*)(ws + SZA);
    char* wbase = ws + 4 * SZA;
    __bf16* qkvT  = (__bf16*)wbase;
    __bf16* projT = qkvT + 576 * 192;
    __bf16* fc1S  = projT + 192 * 192;
    __bf16* fc2S  = fc1S + 768 * 192;
    float*  btab  = (float*)(fc2S + 768 * 192);

    k_transpose<<<(192 * 576 + 255) / 256, 256, 0, stream>>>(qkv_w, qkvT, 192, 576);
    k_transpose<<<(192 * 192 + 255) / 256, 256, 0, stream>>>(proj_w, projT, 192, 192);
    k_prep_fc1<<<(768 * 192 + 255) / 256, 256, 0, stream>>>(fc1_w, fc1S);
    k_prep_fc2<<<(768 * 192 + 255) / 256, 256, 0, stream>>>(fc2_w, fc2S);
    k_bias<<<dim3(4, HEADS), 256, 0, stream>>>(rpb, btab);

    k_ln1win<<<MTOT / 4, 256, 0, stream>>>(x, n1g, n1b, xw);

    // qkv: [M x 192] x [576 x 192]^T -> scatter q/k/v [w,h,t,32]
    k_gemm128<192, 576, 0><<<dim3(MTOT / 128, 5), 256, 0, stream>>>(
        xw, qkvT, qkv_b, qb, nullptr, nullptr, nullptr);

    k_attn_mfma<<<NWIN * HEADS, 64, 0, stream>>>(qb, btab, xw);

    // proj: [M x 192] x [192 x 192]^T -> x1 f32 (image order, +residual)
    k_gemm128<192, 192, 1><<<dim3(MTOT / 128, 2), 256, 0, stream>>>(
        xw, projT, proj_b, nullptr, nullptr, x1, x);

    // fused LN2 + fc1 + GELU + fc2 + residual  (hid stays in LDS)
    k_mlp_fused<<<MTOT / 64, 256, 0, stream>>>(
        x1, n2g, n2b, fc1S, fc1_b, fc2S, fc2_b, outp);
}

// Round 6
// 461.649 us; speedup vs baseline: 1.1364x; 1.1364x over previous
//
#include <hip/hip_runtime.h>
#include <cmath>

typedef __bf16  v8bf  __attribute__((ext_vector_type(8)));
typedef float   v4f   __attribute__((ext_vector_type(4)));

#define HH 56
#define WW2 56
#define SS 3
#define HEADS 6
#define DIM 192
#define HID 768
#define NTOK 49
#define NWIN 2048            // BATCH * 64
#define MTOT (NWIN * NTOK)   // 100352
#define SCALE 0.17677669529663687f

// async global->LDS, 16B per lane. LDS dest must be wave-uniform base + lane*16.
__device__ __forceinline__ void async_cp16(const __bf16* g, __bf16* l) {
    __builtin_amdgcn_global_load_lds(
        (const __attribute__((address_space(1))) void*)g,
        (__attribute__((address_space(3))) void*)l,
        16, 0, 0);
}

// raw workgroup barrier (no implicit vmcnt(0) drain, unlike __syncthreads)
__device__ __forceinline__ void wg_barrier() {
    __builtin_amdgcn_sched_barrier(0);
    __builtin_amdgcn_s_barrier();
    __builtin_amdgcn_sched_barrier(0);
}
#define WAIT_LGKM0() asm volatile("s_waitcnt lgkmcnt(0)" ::: "memory")
#define WAIT_VM(n)   asm volatile("s_waitcnt vmcnt(" #n ")" ::: "memory")

// fast exact-accuracy GELU: erf via Abramowitz-Stegun 7.1.26 (|err|<1.5e-7,
// far below bf16 rounding).
__device__ __forceinline__ float fast_gelu(float x) {
    float z = fabsf(x) * 0.70710678118654752f;
    float t = __builtin_amdgcn_rcpf(1.f + 0.3275911f * z);
    float poly = t * (0.254829592f + t * (-0.284496736f +
                 t * (1.421413741f + t * (-1.453152027f + t * 1.061405429f))));
    float er = 1.f - poly * __expf(-z * z);
    er = (x < 0.f) ? -er : er;
    return 0.5f * x * (1.f + er);
}

// ---------------------------------------------------------------------------
// Weight transpose + f32->bf16 cast: out[n*K + k] = (bf16)in[k*N + n]
// ---------------------------------------------------------------------------
__global__ void k_transpose(const float* __restrict__ in, __bf16* __restrict__ out,
                            int K, int N) {
    int idx = blockIdx.x * 256 + threadIdx.x;
    if (idx >= K * N) return;
    int n = idx / K, k = idx - n * K;
    out[idx] = (__bf16)in[k * N + n];
}

// ---------------------------------------------------------------------------
// Pre-swizzled fc1 weights (staged via global_load_lds, linear LDS dest,
// XOR-swizzled image; guideline 21).  384B row pitch -> 3-bit mask valid.
// fc1S: bf16 idx = n*192 + b16*8 + j  holds fc1_w[(8*(b16^(n&7))+j)*768 + n]
//   -> LDS image: row n_local (stride 384B), byte = (k*2) ^ ((n&7)<<4)
// ---------------------------------------------------------------------------
__global__ void k_prep_fc1(const float* __restrict__ w, __bf16* __restrict__ o) {
    int idx = blockIdx.x * 256 + threadIdx.x;
    if (idx >= HID * DIM) return;
    int n = idx / DIM, rem = idx - n * DIM;
    int b16 = rem >> 3, j = rem & 7;
    int k = 8 * (b16 ^ (n & 7)) + j;
    o[idx] = (__bf16)w[k * HID + n];
}

// ---------------------------------------------------------------------------
// fc2 weights, 32-k chunks, XOR-swizzled image [192 n][32 k] at 64B row
// pitch.  64B pitch -> mask must be < 64: use 2-bit mask ((n>>2)&3)<<4
// (<=48, bijective within each row; k stays < 32 so chunk-local).
// idx = hc*(192*32) + n*32 + c2 ; stored value: k = ((c2*2)^mask)>>1
// ---------------------------------------------------------------------------
__global__ void k_prep_fc2(const float* __restrict__ w, __bf16* __restrict__ o) {
    int idx = blockIdx.x * 256 + threadIdx.x;
    if (idx >= HID * DIM) return;
    int hc = idx / (192 * 32);
    int rem = idx - hc * 192 * 32;
    int n = rem >> 5, c2 = rem & 31;
    int k = ((c2 * 2) ^ (((n >> 2) & 3) << 4)) >> 1;
    o[idx] = (__bf16)w[(hc * 32 + k) * DIM + n];
}

// ---------------------------------------------------------------------------
// Precompute bias tables: bias_tab[type][h][m][n], type in {0=interior,
// 1=right-edge, 2=bottom-edge, 3=corner}.
// ---------------------------------------------------------------------------
__global__ void k_bias(const float* __restrict__ rpb, float* __restrict__ bt) {
    int type = blockIdx.x, h = blockIdx.y;
    for (int idx = threadIdx.x; idx < 4096; idx += 256) {
        int m = idx >> 6, n = idx & 63;
        float v;
        if (m >= 49) v = -1e9f;
        else if (n >= 49) v = 0.f;
        else {
            int ni = n / 7, nj = n % 7, mi = m / 7, mj = m % 7;
            v = rpb[((ni - mi + 6) * 13 + (nj - mj + 6)) * 6 + h];
            int rin = (type & 2) ? ((ni < 4) ? 1 : 2) : 0;
            int rjn = (type & 1) ? ((nj < 4) ? 1 : 2) : 0;
            int rim = (type & 2) ? ((mi < 4) ? 1 : 2) : 0;
            int rjm = (type & 1) ? ((mj < 4) ? 1 : 2) : 0;
            if (rin * 3 + rjn != rim * 3 + rjm) v -= 100.f;
        }
        bt[((size_t)(type * HEADS + h) * 64 + m) * 64 + n] = v;
    }
}

// ---------------------------------------------------------------------------
// LN1 + cyclic shift(-3,-3) + window partition. x f32 -> xw bf16 [w*49+p][c].
// ---------------------------------------------------------------------------
__global__ __launch_bounds__(256) void k_ln1win(const float* __restrict__ x,
                                                const float* __restrict__ g,
                                                const float* __restrict__ bt,
                                                __bf16* __restrict__ xw) {
    int wv = threadIdx.x >> 6, lane = threadIdx.x & 63;
    int t = blockIdx.x * 4 + wv;
    int w = t / NTOK, p = t - w * NTOK;
    int b = w >> 6, wi = w & 63;
    int i = (wi >> 3) * 7 + p / 7;
    int j = (wi & 7) * 7 + p % 7;
    int io = i + SS; if (io >= HH) io -= HH;
    int jo = j + SS; if (jo >= WW2) jo -= WW2;
    const float* src = x + ((size_t)(b * 3136 + io * 56 + jo)) * DIM;
    float v0 = src[lane], v1 = src[lane + 64], v2 = src[lane + 128];
    float s = v0 + v1 + v2, s2 = v0 * v0 + v1 * v1 + v2 * v2;
    #pragma unroll
    for (int off = 1; off < 64; off <<= 1) {
        s  += __shfl_xor(s, off);
        s2 += __shfl_xor(s2, off);
    }
    float mu = s * (1.f / 192.f);
    float rstd = rsqrtf(s2 * (1.f / 192.f) - mu * mu + 1e-5f);
    __bf16* dst = xw + (size_t)t * DIM;
    dst[lane]       = (__bf16)((v0 - mu) * rstd * g[lane]       + bt[lane]);
    dst[lane + 64]  = (__bf16)((v1 - mu) * rstd * g[lane + 64]  + bt[lane + 64]);
    dst[lane + 128] = (__bf16)((v2 - mu) * rstd * g[lane + 128] + bt[lane + 128]);
}

// ---------------------------------------------------------------------------
// 128x128-tile MFMA GEMM, double-buffered LDS + counted vmcnt (T3/T4).
// MODE 0: qkv scatter -> qb/kb/vb [w,h,t,32] bf16 (q scaled).
// MODE 1: proj -> outf = x1 (window-reverse scatter) + xres, f32
// ---------------------------------------------------------------------------
template<int KDIM, int NDIM, int MODE>
__global__ __launch_bounds__(256) void k_gemm128(const __bf16* __restrict__ A,
                                                 const __bf16* __restrict__ Wt,
                                                 const float* __restrict__ bias,
                                                 __bf16* __restrict__ outb,
                                                 const float* __restrict__ x1in,
                                                 float* __restrict__ outf,
                                                 const float* __restrict__ xres) {
    __shared__ __bf16 lA[2][128 * 32];
    __shared__ __bf16 lB[2][128 * 32];
    const int tid = threadIdx.x;
    const int m0 = blockIdx.x * 128, n0 = blockIdx.y * 128;
    const int wv = tid >> 6, lane = tid & 63;
    const int wm = (wv >> 1) * 64, wn = (wv & 1) * 64;
    const int lrow = lane & 15, lq = lane >> 4;
    const int grow = tid >> 2, gkc = (tid & 3) * 8;

    auto stage = [&](int kk, int b) {
        #pragma unroll
        for (int c = 0; c < 2; c++) {
            int r = grow + c * 64;
            async_cp16(A + (size_t)(m0 + r) * KDIM + kk + gkc, lA[b] + tid * 8 + c * 2048);
            int rb = n0 + r;
            if (NDIM % 128) rb = (rb < NDIM) ? rb : (NDIM - 1);
            async_cp16(Wt + (size_t)rb * KDIM + kk + gkc, lB[b] + tid * 8 + c * 2048);
        }
    };
    stage(0, 0);
    stage(32, 1);

    v4f acc[4][4] = {};
    #pragma unroll
    for (int kk = 0; kk < KDIM; kk += 32) {
        const int b = (kk >> 5) & 1;
        if (kk + 32 < KDIM) { WAIT_VM(4); } else { WAIT_VM(0); }
        wg_barrier();
        v8bf af[4], bf[4];
        #pragma unroll
        for (int i = 0; i < 4; i++) {
            af[i] = *(const v8bf*)(lA[b] + (wm + i * 16 + lrow) * 32 + lq * 8);
            bf[i] = *(const v8bf*)(lB[b] + (wn + i * 16 + lrow) * 32 + lq * 8);
        }
        #pragma unroll
        for (int i = 0; i < 4; i++)
        #pragma unroll
        for (int j = 0; j < 4; j++)
            acc[i][j] = __builtin_amdgcn_mfma_f32_16x16x32_bf16(af[i], bf[j], acc[i][j], 0, 0, 0);
        wg_barrier();
        if (kk + 64 < KDIM) stage(kk + 64, b);
    }
    #pragma unroll
    for (int i = 0; i < 4; i++)
    #pragma unroll
    for (int j = 0; j < 4; j++) {
        int col = n0 + wn + j * 16 + lrow;
        if (NDIM % 128 && col >= NDIM) continue;
        float bv = bias[col];
        #pragma unroll
        for (int r = 0; r < 4; r++) {
            int row = m0 + wm + i * 16 + lq * 4 + r;
            float v = acc[i][j][r] + bv;
            if (MODE == 0) {
                __bf16* kbp = outb + (size_t)MTOT * DIM;
                __bf16* vbp = kbp + (size_t)MTOT * DIM;
                int which = col / DIM, rem = col - which * DIM;
                int hh = rem >> 5, d = rem & 31;
                int w = row / NTOK, p = row - w * NTOK;
                size_t off = ((size_t)(w * HEADS + hh) * NTOK + p) * 32 + d;
                if (which == 0)      outb[off] = (__bf16)(v * SCALE);
                else if (which == 1) kbp[off] = (__bf16)v;
                else                 vbp[off] = (__bf16)v;
            } else {  // proj: window-reverse + unshift + residual
                int w = row / NTOK, p = row - w * NTOK;
                int bimg = w >> 6, wi = w & 63;
                int ii = (wi >> 3) * 7 + p / 7;
                int jj = (wi & 7) * 7 + p % 7;
                int io = ii + SS; if (io >= HH) io -= HH;
                int jo = jj + SS; if (jo >= WW2) jo -= WW2;
                size_t o = ((size_t)(bimg * 3136 + io * 56 + jo)) * DIM + col;
                outf[o] = v + xres[o];
            }
        }
    }
}

// ---------------------------------------------------------------------------
// MFMA windowed attention: one wave per (window, head), 64-thread blocks.
// ---------------------------------------------------------------------------
__global__ __launch_bounds__(64) void k_attn_mfma(const __bf16* __restrict__ qb,
                                                  const float* __restrict__ bias_tab,
                                                  __bf16* __restrict__ ao) {
    __shared__ __bf16 Pl[64 * 72];
    __shared__ __bf16 VTl[32 * 72];
    const __bf16* kb = qb + (size_t)MTOT * DIM;
    const __bf16* vb = kb + (size_t)MTOT * DIM;
    int wh = blockIdx.x;
    int w = wh / HEADS, h = wh - w * HEADS;
    int lane = threadIdx.x & 63;
    int c = lane & 15, q = lane >> 4;
    const size_t base = (size_t)wh * (NTOK * 32);

    for (int idx = lane; idx < 32 * 16; idx += 64)
        VTl[(idx >> 4) * 72 + 48 + (idx & 15)] = (__bf16)0.f;
    #pragma unroll
    for (int it = 0; it < 4; it++) {
        int idx = it * 64 + lane;
        if (idx < NTOK * 4) {
            int t = idx >> 2, d0 = (idx & 3) * 8;
            v8bf vv = *(const v8bf*)(vb + base + t * 32 + d0);
            #pragma unroll
            for (int ii = 0; ii < 8; ii++) VTl[(d0 + ii) * 72 + t] = vv[ii];
        }
    }
    v8bf af[4], bf[4];
    #pragma unroll
    for (int rt = 0; rt < 4; rt++) {
        int t = rt * 16 + c; t = (t > 48) ? 48 : t;
        af[rt] = *(const v8bf*)(qb + base + t * 32 + q * 8);
        bf[rt] = *(const v8bf*)(kb + base + t * 32 + q * 8);
    }
    v4f S[4][4] = {};
    #pragma unroll
    for (int rt = 0; rt < 4; rt++)
    #pragma unroll
    for (int ct = 0; ct < 4; ct++)
        S[rt][ct] = __builtin_amdgcn_mfma_f32_16x16x32_bf16(af[rt], bf[ct], S[rt][ct], 0, 0, 0);
    int wi = w & 63;
    int type = (((wi >> 3) == 7) ? 2 : 0) + (((wi & 7) == 7) ? 1 : 0);
    const float* bt = bias_tab + (size_t)(type * HEADS + h) * 4096;
    #pragma unroll
    for (int rt = 0; rt < 4; rt++)
    #pragma unroll
    for (int ct = 0; ct < 4; ct++) {
        v4f bv = *(const v4f*)(bt + (ct * 16 + c) * 64 + rt * 16 + q * 4);
        S[rt][ct] += bv;
    }
    v4f mx4[4], inv4[4];
    #pragma unroll
    for (int rt = 0; rt < 4; rt++) {
        v4f m;
        #pragma unroll
        for (int r = 0; r < 4; r++)
            m[r] = fmaxf(fmaxf(S[rt][0][r], S[rt][1][r]), fmaxf(S[rt][2][r], S[rt][3][r]));
        #pragma unroll
        for (int off = 1; off < 16; off <<= 1) {
            #pragma unroll
            for (int r = 0; r < 4; r++) m[r] = fmaxf(m[r], __shfl_xor(m[r], off));
        }
        mx4[rt] = m;
    }
    #pragma unroll
    for (int rt = 0; rt < 4; rt++) {
        v4f dsum = {};
        #pragma unroll
        for (int ct = 0; ct < 4; ct++) {
            #pragma unroll
            for (int r = 0; r < 4; r++) {
                float e = __expf(S[rt][ct][r] - mx4[rt][r]);
                dsum[r] += e;
                Pl[(rt * 16 + q * 4 + r) * 72 + ct * 16 + c] = (__bf16)e;
            }
        }
        #pragma unroll
        for (int off = 1; off < 16; off <<= 1) {
            #pragma unroll
            for (int r = 0; r < 4; r++) dsum[r] += __shfl_xor(dsum[r], off);
        }
        #pragma unroll
        for (int r = 0; r < 4; r++) inv4[rt][r] = 1.f / dsum[r];
    }
    __syncthreads();
    v4f O[4][2] = {};
    #pragma unroll
    for (int k2 = 0; k2 < 2; k2++) {
        v8bf pa[4], pb[2];
        #pragma unroll
        for (int rt = 0; rt < 4; rt++)
            pa[rt] = *(const v8bf*)(Pl + (rt * 16 + c) * 72 + k2 * 32 + q * 8);
        #pragma unroll
        for (int ct = 0; ct < 2; ct++)
            pb[ct] = *(const v8bf*)(VTl + (ct * 16 + c) * 72 + k2 * 32 + q * 8);
        #pragma unroll
        for (int rt = 0; rt < 4; rt++)
        #pragma unroll
        for (int ct = 0; ct < 2; ct++)
            O[rt][ct] = __builtin_amdgcn_mfma_f32_16x16x32_bf16(pa[rt], pb[ct], O[rt][ct], 0, 0, 0);
    }
    __bf16* aop = ao + (size_t)(w * NTOK) * DIM + h * 32;
    #pragma unroll
    for (int rt = 0; rt < 4; rt++)
    #pragma unroll
    for (int r = 0; r < 4; r++) {
        int row = rt * 16 + q * 4 + r;
        if (row < NTOK) {
            #pragma unroll
            for (int ct = 0; ct < 2; ct++)
                aop[(size_t)row * DIM + ct * 16 + c] = (__bf16)(O[rt][ct][r] * inv4[rt][r]);
        }
    }
}

// ---------------------------------------------------------------------------
// Fused MLP v6: LN2 + fc1 + GELU + fc2 + residual. BM=64, HC=32 (24 chunks).
// Counted-vmcnt ping-pong (T3/T4); 40,704 B LDS -> up to 4 blocks/CU.
// launch_bounds(256,2): VGPR <=128 so no spill (v4's (256,4) capped VGPR=64
// -> ~90MB scratch traffic).  64B-pitch buffers use VALID 2-bit XOR masks
// (((row>>2)&3)<<4 <= 48 < 64): v5's 3-bit mask overflowed the row -> wrong
// data (guideline 21: producer/reader permutation must be the same bijection).
//
// LDS map (40,704 B):
//   [0,24576)      aT (LN2 image, 64 x 384B swz (row&7)<<4) -> recycled:
//     [0,12288)      bufX: fc2 chunk, row n (64B), byte=(k*2)^(((n>>2)&3)<<4)
//     [12288,16384)  lH:   GELU chunk, row r (64B), byte=(c*2)^(((r>>2)&3)<<4)
//   [24576,36864)  bufY: fc1 chunk [32 n][192 k] swz (n&7)<<4 (384B rows)
//   [36864,39936)  lB1 (768 f32);  [39936,40704) lB2 (192 f32)
// Stage = 3 async_cp16/thread -> waits are vmcnt(3).
// ---------------------------------------------------------------------------
__global__ __launch_bounds__(256, 2) void k_mlp_fused(
        const float* __restrict__ x1,
        const float* __restrict__ n2g, const float* __restrict__ n2b,
        const __bf16* __restrict__ fc1S, const float* __restrict__ fc1b,
        const __bf16* __restrict__ fc2S, const float* __restrict__ fc2b,
        float* __restrict__ out) {
    __shared__ __align__(16) char sm[40704];
    char* bufX = sm;                     // 12288 (after LN)
    char* lH   = sm + 12288;             //  4096 (after LN)
    char* bufY = sm + 24576;             // 12288
    float* lB1 = (float*)(sm + 36864);   //  3072
    float* lB2 = (float*)(sm + 39936);   //   768
    const int tid = threadIdx.x;
    const int wv = tid >> 6, lane = tid & 63;
    const int lrow = lane & 15, lq = lane >> 4;
    const int m0 = blockIdx.x * 64;

    // prefetch W1 chunk 0 into bufY (drained by LN's value-consumption waits)
    #pragma unroll
    for (int p = 0; p < 3; ++p)
        async_cp16(fc1S + p * 2048 + tid * 8, (__bf16*)bufY + p * 2048 + tid * 8);

    // stage biases to LDS (loop body must stay free of extra vmem ops)
    #pragma unroll
    for (int p = 0; p < 3; ++p) lB1[p * 256 + tid] = fc1b[p * 256 + tid];
    if (tid < 192) lB2[tid] = fc2b[tid];

    // ---- Phase 0: LN2 of 64 rows into aT=sm[0..24576) (swz); 16 rows/wave
    {
        float g0 = n2g[lane], g1 = n2g[lane + 64], g2 = n2g[lane + 128];
        float b0 = n2b[lane], b1 = n2b[lane + 64], b2 = n2b[lane + 128];
        #pragma unroll 4
        for (int it = 0; it < 16; ++it) {
            int row = wv * 16 + it;
            const float* src = x1 + (size_t)(m0 + row) * DIM;
            float v0 = src[lane], v1 = src[lane + 64], v2 = src[lane + 128];
            float s = v0 + v1 + v2, s2 = v0 * v0 + v1 * v1 + v2 * v2;
            #pragma unroll
            for (int off = 1; off < 64; off <<= 1) {
                s  += __shfl_xor(s, off);
                s2 += __shfl_xor(s2, off);
            }
            float mu = s * (1.f / 192.f);
            float rstd = rsqrtf(s2 * (1.f / 192.f) - mu * mu + 1e-5f);
            char* rb = sm + row * 384;
            int xo = (row & 7) << 4;
            *(__bf16*)(rb + ((lane * 2)       ^ xo)) = (__bf16)((v0 - mu) * rstd * g0 + b0);
            *(__bf16*)(rb + ((lane * 2 + 128) ^ xo)) = (__bf16)((v1 - mu) * rstd * g1 + b1);
            *(__bf16*)(rb + ((lane * 2 + 256) ^ xo)) = (__bf16)((v2 - mu) * rstd * g2 + b2);
        }
    }
    WAIT_LGKM0();
    wg_barrier();        // aT + biases visible; W1[0] landed

    // ---- A fragments -> registers; aT space then recycled (bufX/lH) ----
    const int wm  = (wv >> 1) * 32;   // row-tile base
    const int wc1 = (wv & 1) * 16;    // fc1 col base within 32-chunk
    const int wn  = (wv & 1) * 96;    // fc2 col base (192 total)
    v8bf afr[2][6];
    #pragma unroll
    for (int i = 0; i < 2; ++i) {
        int ra = wm + i * 16 + lrow;
        #pragma unroll
        for (int ks = 0; ks < 6; ++ks)
            afr[i][ks] = *(const v8bf*)(sm + ra * 384 + ((ks * 64 + lq * 16) ^ ((ra & 7) << 4)));
    }
    WAIT_LGKM0();        // frags in VGPRs before DMA overwrites the region
    wg_barrier();

    // issue W2 chunk 0 into bufX (lands under fc1[0] compute)
    #pragma unroll
    for (int p = 0; p < 3; ++p)
        async_cp16(fc2S + p * 2048 + tid * 8, (__bf16*)bufX + p * 2048 + tid * 8);

    v4f oacc[2][6] = {};
    for (int hc = 0; hc < 24; ++hc) {
        int hn = hc + 1; if (hn == 24) hn = 0;   // wrapped: keeps waits uniform
        // ---- fc1: hid_chunk[64][32] = afr * W1[hc](bufY)^T ----
        v4f hacc[2] = {};
        __builtin_amdgcn_s_setprio(1);
        #pragma unroll
        for (int ks = 0; ks < 6; ++ks) {
            int rw = wc1 + lrow;
            v8bf bw = *(const v8bf*)(bufY + rw * 384 + ((ks * 64 + lq * 16) ^ ((rw & 7) << 4)));
            #pragma unroll
            for (int i = 0; i < 2; ++i)
                hacc[i] = __builtin_amdgcn_mfma_f32_16x16x32_bf16(afr[i][ks], bw, hacc[i], 0, 0, 0);
        }
        __builtin_amdgcn_s_setprio(0);
        // ---- bias + fast GELU -> lH (swz, 64B pitch, 2-bit mask = lq) ----
        {
            float bv = lB1[hc * 32 + wc1 + lrow];
            #pragma unroll
            for (int i = 0; i < 2; ++i)
            #pragma unroll
            for (int r = 0; r < 4; ++r) {
                int row = wm + i * 16 + lq * 4 + r;
                int col = wc1 + lrow;
                float hv = hacc[i][r] + bv;
                *(__bf16*)(lH + row * 64 + ((col * 2) ^ (((row >> 2) & 3) << 4))) =
                    (__bf16)fast_gelu(hv);
            }
        }
        WAIT_LGKM0();
        wg_barrier();                      // lH visible; bufY reads done everywhere
        {   // issue W1[hn] -> bufY (lands under fc2 compute)
            const __bf16* s1 = fc1S + (size_t)hn * (32 * 192);
            #pragma unroll
            for (int p = 0; p < 3; ++p)
                async_cp16(s1 + p * 2048 + tid * 8, (__bf16*)bufY + p * 2048 + tid * 8);
        }
        WAIT_VM(3);                        // W2[hc] (older 3) landed; W1[hn] in flight
        wg_barrier();                      // -> all waves' W2[hc] landed
        // ---- fc2: oacc += lH[64x32] * W2[hc](bufX)^T (192 cols, K=32) ----
        __builtin_amdgcn_s_setprio(1);
        {
            v8bf pa[2], pb[6];
            #pragma unroll
            for (int i = 0; i < 2; ++i) {
                int ra = wm + i * 16 + lrow;
                pa[i] = *(const v8bf*)(lH + ra * 64 + ((lq * 16) ^ (((ra >> 2) & 3) << 4)));
            }
            #pragma unroll
            for (int j = 0; j < 6; ++j) {
                int rw = wn + j * 16 + lrow;
                pb[j] = *(const v8bf*)(bufX + rw * 64 + ((lq * 16) ^ (((rw >> 2) & 3) << 4)));
            }
            #pragma unroll
            for (int i = 0; i < 2; ++i)
            #pragma unroll
            for (int j = 0; j < 6; ++j)
                oacc[i][j] = __builtin_amdgcn_mfma_f32_16x16x32_bf16(pa[i], pb[j], oacc[i][j], 0, 0, 0);
        }
        __builtin_amdgcn_s_setprio(0);
        WAIT_LGKM0();
        wg_barrier();                      // bufX/lH reads done everywhere
        {   // issue W2[hn] -> bufX (lands under next fc1 compute)
            const __bf16* s2 = fc2S + (size_t)hn * (192 * 32);
            #pragma unroll
            for (int p = 0; p < 3; ++p)
                async_cp16(s2 + p * 2048 + tid * 8, (__bf16*)bufX + p * 2048 + tid * 8);
        }
        WAIT_VM(3);                        // W1[hn] (older 3) landed; W2[hn] in flight
        wg_barrier();
    }
    WAIT_VM(0);   // drain wrapped redundant loads
    // ---- epilogue: out = oacc + fc2b + x1 (residual) ----
    #pragma unroll
    for (int i = 0; i < 2; ++i)
    #pragma unroll
    for (int j = 0; j < 6; ++j) {
        int col = wn + j * 16 + lrow;
        float bv = lB2[col];
        #pragma unroll
        for (int r = 0; r < 4; ++r) {
            int row = m0 + wm + i * 16 + lq * 4 + r;
            size_t o = (size_t)row * DIM + col;
            out[o] = oacc[i][j][r] + bv + x1[o];
        }
    }
}

// ---------------------------------------------------------------------------
extern "C" void kernel_launch(void* const* d_in, const int* in_sizes, int n_in,
                              void* d_out, int out_size, void* d_ws, size_t ws_size,
                              hipStream_t stream) {
    const float* x      = (const float*)d_in[0];
    const float* n1g    = (const float*)d_in[1];
    const float* n1b    = (const float*)d_in[2];
    const float* qkv_w  = (const float*)d_in[3];
    const float* qkv_b  = (const float*)d_in[4];
    const float* rpb    = (const float*)d_in[5];
    const float* proj_w = (const float*)d_in[6];
    const float* proj_b = (const float*)d_in[7];
    const float* n2g    = (const float*)d_in[8];
    const float* n2b    = (const float*)d_in[9];
    const float* fc1_w  = (const float*)d_in[10];
    const float* fc1_b  = (const float*)d_in[11];
    const float* fc2_w  = (const float*)d_in[12];
    const float* fc2_b  = (const float*)d_in[13];
    float* outp = (float*)d_out;

    char* ws = (char*)d_ws;
    const size_t SZA = (size_t)MTOT * DIM * 2;      // 38,535,168
    __bf16* xw = (__bf16*)ws;
    __bf16* qb = (__bf16*)(ws + SZA);
    float*  x1 = (float*)(ws + SZA);
    char* wbase = ws + 4 * SZA;
    __bf16* qkvT  = (__bf16*)wbase;
    __bf16* projT = qkvT + 576 * 192;
    __bf16* fc1S  = projT + 192 * 192;
    __bf16* fc2S  = fc1S + 768 * 192;
    float*  btab  = (float*)(fc2S + 768 * 192);

    k_transpose<<<(192 * 576 + 255) / 256, 256, 0, stream>>>(qkv_w, qkvT, 192, 576);
    k_transpose<<<(192 * 192 + 255) / 256, 256, 0, stream>>>(proj_w, projT, 192, 192);
    k_prep_fc1<<<(768 * 192 + 255) / 256, 256, 0, stream>>>(fc1_w, fc1S);
    k_prep_fc2<<<(768 * 192 + 255) / 256, 256, 0, stream>>>(fc2_w, fc2S);
    k_bias<<<dim3(4, HEADS), 256, 0, stream>>>(rpb, btab);

    k_ln1win<<<MTOT / 4, 256, 0, stream>>>(x, n1g, n1b, xw);

    // qkv: [M x 192] x [576 x 192]^T -> scatter q/k/v [w,h,t,32]
    k_gemm128<192, 576, 0><<<dim3(MTOT / 128, 5), 256, 0, stream>>>(
        xw, qkvT, qkv_b, qb, nullptr, nullptr, nullptr);

    k_attn_mfma<<<NWIN * HEADS, 64, 0, stream>>>(qb, btab, xw);

    // proj: [M x 192] x [192 x 192]^T -> x1 f32 (image order, +residual)
    k_gemm128<192, 192, 1><<<dim3(MTOT / 128, 2), 256, 0, stream>>>(
        xw, projT, proj_b, nullptr, nullptr, x1, x);

    // fused LN2 + fc1 + GELU + fc2 + residual  (hid stays in LDS)
    k_mlp_fused<<<MTOT / 64, 256, 0, stream>>>(
        x1, n2g, n2b, fc1S, fc1_b, fc2S, fc2_b, outp);
}